// Round 11
// baseline (714.561 us; speedup 1.0000x reference)
//
#include <hip/hip_runtime.h>

typedef unsigned short u16;
typedef unsigned int u32;
typedef float f32x4 __attribute__((ext_vector_type(4)));
typedef short s16x8 __attribute__((ext_vector_type(8)));

__device__ __forceinline__ u16 f2bf(float v) {
  union { float f; u32 u; } c; c.f = v;
  u32 r = c.u + 0x7FFFu + ((c.u >> 16) & 1u);
  return (u16)(r >> 16);
}
__device__ __forceinline__ float bf2f(u16 h) {
  union { u32 u; float f; } c; c.u = ((u32)h) << 16;
  return c.f;
}
__device__ __forceinline__ float sigm(float x) { return 1.0f / (1.0f + expf(-x)); }

__device__ __forceinline__ void gload_lds16(const void* g, void* l) {
  __builtin_amdgcn_global_load_lds(
      (const __attribute__((address_space(1))) void*)g,
      (__attribute__((address_space(3))) void*)l, 16, 0, 0);
}

#define BARRIER() asm volatile("s_barrier" ::: "memory")
#define WAIT_LGKM0() asm volatile("s_waitcnt lgkmcnt(0)" ::: "memory")
#define VMCNT(n) asm volatile("s_waitcnt vmcnt(" #n ")" ::: "memory")

// ===========================================================================
// OLD 128x128 kernel (round-1, known good) — fallback path only.
// ===========================================================================
__device__ __forceinline__ void stage_tile(const u16* __restrict__ G, int ld,
                                           int row0, int k0, u16* buf, int tid) {
#pragma unroll
  for (int r = 0; r < 2; ++r) {
    int ci = r * 256 + tid;
    int row = ci >> 2;
    int c = (ci & 3) * 8;
    gload_lds16(G + (size_t)(row0 + row) * ld + k0 + c, buf + (size_t)ci * 8);
  }
}

template <int ASRC, int BSPL, int EPI>
__global__ __launch_bounds__(256) void gemm_kernel(
    const float* __restrict__ Af, const u16* __restrict__ Ah, const u16* __restrict__ Al,
    const u16* __restrict__ Bh, const u16* __restrict__ Bl,
    const float* __restrict__ bias,
    float* __restrict__ Of, u16* __restrict__ Oh, u16* __restrict__ Ol,
    int M, int N, int K) {
  constexpr int BM = 128, BN = 128, BK = 32;
  constexpr bool SPLIT = (ASRC != 2) && (BSPL != 0);
  __shared__ __attribute__((aligned(16))) u16 Ahs[BM * BK];
  __shared__ __attribute__((aligned(16))) u16 Bhs[BN * BK];
  __shared__ __attribute__((aligned(16))) u16 Als[(ASRC != 2) ? BM * BK : 8];
  __shared__ __attribute__((aligned(16))) u16 Bls[BSPL ? BN * BK : 8];

  const int tid = threadIdx.x;
  const int lane = tid & 63;
  const int wid = tid >> 6;
  const int m0 = blockIdx.y * BM;
  const int n0 = blockIdx.x * BN;
  const int wm = (wid >> 1) * 64;
  const int wn = (wid & 1) * 64;

  f32x4 acc[4][4];
#pragma unroll
  for (int i = 0; i < 4; ++i)
#pragma unroll
    for (int j = 0; j < 4; ++j) acc[i][j] = (f32x4){0.f, 0.f, 0.f, 0.f};

  const int arow = lane & 15;
  const int asel = (lane >> 4) * 8;

  for (int k0 = 0; k0 < K; k0 += BK) {
    if constexpr (ASRC == 0) {
      int row = tid >> 1, cb = (tid & 1) << 4;
      const float* s = Af + (size_t)(m0 + row) * K + k0 + cb;
      float xs[16];
      *(float4*)(xs + 0)  = *(const float4*)(s + 0);
      *(float4*)(xs + 4)  = *(const float4*)(s + 4);
      *(float4*)(xs + 8)  = *(const float4*)(s + 8);
      *(float4*)(xs + 12) = *(const float4*)(s + 12);
      s16x8 hv[2], lv[2];
#pragma unroll
      for (int q = 0; q < 2; ++q)
#pragma unroll
        for (int i = 0; i < 8; ++i) {
          float xv = xs[q * 8 + i];
          u16 h = f2bf(xv);
          hv[q][i] = (short)h;
          lv[q][i] = (short)f2bf(xv - bf2f(h));
        }
      *(s16x8*)(&Ahs[row * BK + cb])     = hv[0];
      *(s16x8*)(&Ahs[row * BK + cb + 8]) = hv[1];
      *(s16x8*)(&Als[row * BK + cb])     = lv[0];
      *(s16x8*)(&Als[row * BK + cb + 8]) = lv[1];
    } else if constexpr (ASRC == 1) {
      stage_tile(Ah, K, m0, k0, Ahs, tid);
      stage_tile(Al, K, m0, k0, Als, tid);
    } else {
      stage_tile(Ah, K, m0, k0, Ahs, tid);
    }
    stage_tile(Bh, K, n0, k0, Bhs, tid);
    if constexpr (BSPL) stage_tile(Bl, K, n0, k0, Bls, tid);
    __syncthreads();

    s16x8 a_h[4], b_h[4];
    s16x8 a_l[4], b_l[4];
#pragma unroll
    for (int i = 0; i < 4; ++i) {
      a_h[i] = *(const s16x8*)(&Ahs[(wm + i * 16 + arow) * BK + asel]);
      b_h[i] = *(const s16x8*)(&Bhs[(wn + i * 16 + arow) * BK + asel]);
      if constexpr (SPLIT) {
        a_l[i] = *(const s16x8*)(&Als[(wm + i * 16 + arow) * BK + asel]);
        b_l[i] = *(const s16x8*)(&Bls[(wn + i * 16 + arow) * BK + asel]);
      }
    }
#pragma unroll
    for (int mi = 0; mi < 4; ++mi)
#pragma unroll
      for (int ni = 0; ni < 4; ++ni) {
        f32x4 c = acc[mi][ni];
        c = __builtin_amdgcn_mfma_f32_16x16x32_bf16(a_h[mi], b_h[ni], c, 0, 0, 0);
        if constexpr (SPLIT) {
          c = __builtin_amdgcn_mfma_f32_16x16x32_bf16(a_h[mi], b_l[ni], c, 0, 0, 0);
          c = __builtin_amdgcn_mfma_f32_16x16x32_bf16(a_l[mi], b_h[ni], c, 0, 0, 0);
        }
        acc[mi][ni] = c;
      }
    __syncthreads();
  }

#pragma unroll
  for (int mi = 0; mi < 4; ++mi) {
#pragma unroll
    for (int ni = 0; ni < 4; ++ni) {
      int gcol = n0 + wn + ni * 16 + (lane & 15);
      float bv = bias[gcol];
#pragma unroll
      for (int r = 0; r < 4; ++r) {
        int grow = m0 + wm + mi * 16 + (lane >> 4) * 4 + r;
        float v = acc[mi][ni][r] + bv;
        size_t o = (size_t)grow * N + gcol;
        if constexpr (EPI == 0) {
          v = sigm(v);
          u16 h = f2bf(v);
          Oh[o] = h;
          Ol[o] = f2bf(v - bf2f(h));
        } else if constexpr (EPI == 1) {
          Of[o] = sigm(v);
        } else if constexpr (EPI == 2) {
          Oh[o] = f2bf(sigm(v));
        } else {
          Of[o] = v;
        }
      }
    }
  }
}

// ===========================================================================
// gemm8p v2 (G3/G4): 256^2 K-step 64, 16x16x32. Barrier-audit applied:
// post-MFMA barriers removed (8 -> 5 barriers/tile); staging moved so every
// in-place write issues >= 1 barrier after the readers' retiring lgkm:
//  - A(t+1)h1 -> other buf at P0 (last reads t-1 P0/P2, retired < B3(t-1)).
//  - B(t+2) h0+h1 in-place at P3 region (B h0/h1 last reads P0/P1, retired
//    before any wave arrives B2; write issues after passing B2).
//  - A(t+2)h0 in-place AFTER B3 (A g1 reads at P2 retired < arrival B3).
// vmcnt ledger: 14 outstanding at end-of-t; vmcnt(6) retires t-1's P3 six +
// A(t+1)h1; t==NT-2 -> vmcnt(0) (nothing staged at its P3).
// ===========================================================================
__device__ __forceinline__ void stage_half(const u16* __restrict__ G, int ldk,
                                           int row0, int koff, u16* dst, int tid) {
#pragma unroll
  for (int r = 0; r < 2; ++r) {
    int ci = r * 512 + tid;            // 16B chunk, 0..1023 (128 rows x 64 cols)
    int rw = ci >> 3;                  // physical LDS row
    int gl = (ci & 7) ^ (rw & 7);      // inverse-swizzled source granule
    gload_lds16(G + (size_t)(row0 + rw) * ldk + koff + gl * 8, dst + ci * 8);
  }
}

template <int G, int J0>
__device__ __forceinline__ void mfma_block(f32x4 (&acc)[8][4],
                                           const s16x8 (&a)[4][2],
                                           const s16x8 (&b)[4][2]) {
  __builtin_amdgcn_s_setprio(1);
#pragma unroll
  for (int j = 0; j < 2; ++j)
#pragma unroll
    for (int i = 0; i < 4; ++i)
#pragma unroll
      for (int ks = 0; ks < 2; ++ks)
        acc[G * 4 + i][J0 + j] = __builtin_amdgcn_mfma_f32_16x16x32_bf16(
            a[i][ks], b[J0 + j][ks], acc[G * 4 + i][J0 + j], 0, 0, 0);
  __builtin_amdgcn_s_setprio(0);
}

// EPI: 2 sigmoid->bf16, 3 linear->fp32
template <int STREAMS, int EPI>
__global__ __launch_bounds__(512, 2) void gemm8p_kernel(
    const u16* __restrict__ Ah, const u16* __restrict__ Al,
    const u16* __restrict__ Bh, const u16* __restrict__ Bl,
    const float* __restrict__ bias,
    float* __restrict__ Of, u16* __restrict__ Oh, u16* __restrict__ Ol,
    int M, int N, int K) {
  __shared__ __attribute__((aligned(16))) u16 lds[2][2][256 * 64];  // 128 KiB
  const int tid = threadIdx.x;
  const int lane = tid & 63;
  const int wid = tid >> 6;
  const int wr = wid >> 2, wc = wid & 3;  // 2M x 4N wave grid

  const int gx = gridDim.x;
  int nwg = gx * gridDim.y;
  int orig = blockIdx.y * gx + blockIdx.x;
  int swz = (orig & 7) * (nwg >> 3) + (orig >> 3);  // nwg % 8 == 0 (bijective)
  int bx = swz % gx, by = swz / gx;
  const int m0 = by * 256, n0 = bx * 256;

  const int NT = (STREAMS == 3) ? 3 * (K >> 6) : (K >> 6);

  f32x4 acc[8][4];
#pragma unroll
  for (int i = 0; i < 8; ++i)
#pragma unroll
    for (int j = 0; j < 4; ++j) acc[i][j] = (f32x4){0.f, 0.f, 0.f, 0.f};

  const int aoff = (wr * 128 + (lane & 15)) * 64;
  const int boff = (wc * 64 + (lane & 15)) * 64;
  int kst[2];
#pragma unroll
  for (int ks = 0; ks < 2; ++ks)
    kst[ks] = ((ks * 4 + (lane >> 4)) ^ (lane & 7)) * 8;

  const u16* p; int ko;
  auto selA = [&](int s, const u16** pp, int* o) {
    if constexpr (STREAMS == 3) {
      int d = s / 3, r = s - d * 3;
      *pp = (r == 2) ? Al : Ah;
      *o = d << 6;
    } else { *pp = Ah; *o = s << 6; }
  };
  auto selB = [&](int s, const u16** pp, int* o) {
    if constexpr (STREAMS == 3) {
      int d = s / 3, r = s - d * 3;
      *pp = (r == 1) ? Bl : Bh;
      *o = d << 6;
    } else { *pp = Bh; *o = s << 6; }
  };

  // prologue: K0 {Bh0,Bh1,Ah0,Ah1} -> buf0 ; K1 {Bh0,Bh1,Ah0} -> buf1
  selB(0, &p, &ko);
  stage_half(p, K, n0, ko, &lds[0][1][0], tid);
  stage_half(p, K, n0 + 128, ko, &lds[0][1][128 * 64], tid);
  selA(0, &p, &ko);
  stage_half(p, K, m0, ko, &lds[0][0][0], tid);
  stage_half(p, K, m0 + 128, ko, &lds[0][0][128 * 64], tid);
  selB(1, &p, &ko);
  stage_half(p, K, n0, ko, &lds[1][1][0], tid);
  stage_half(p, K, n0 + 128, ko, &lds[1][1][128 * 64], tid);
  selA(1, &p, &ko);
  stage_half(p, K, m0, ko, &lds[1][0][0], tid);
  VMCNT(6);  // K0 fully landed
  BARRIER();

  for (int t = 0; t < NT; ++t) {
    const int bt = t & 1;
    const u16* As = &lds[bt][0][0];
    const u16* Bs = &lds[bt][1][0];
    u16* Adst_n = &lds[bt ^ 1][0][0];
    s16x8 a[4][2], b[4][2];

    // ---- P0: read a(g0), b(cols 0,1); stage A(t+1)h1 (other buffer)
#pragma unroll
    for (int ks = 0; ks < 2; ++ks) {
#pragma unroll
      for (int i = 0; i < 4; ++i)
        a[i][ks] = *(const s16x8*)(As + aoff + i * 1024 + kst[ks]);
#pragma unroll
      for (int j = 0; j < 2; ++j)
        b[j][ks] = *(const s16x8*)(Bs + boff + j * 1024 + kst[ks]);
    }
    if (t + 1 < NT) {
      selA(t + 1, &p, &ko);
      stage_half(p, K, m0 + 128, ko, Adst_n + 128 * 64, tid);
    }
    BARRIER(); WAIT_LGKM0();
    mfma_block<0, 0>(acc, a, b);

    // ---- P1: read b(cols 2,3)
#pragma unroll
    for (int ks = 0; ks < 2; ++ks)
#pragma unroll
      for (int j = 2; j < 4; ++j)
        b[j][ks] = *(const s16x8*)(Bs + boff + j * 1024 + kst[ks]);
    BARRIER(); WAIT_LGKM0();
    mfma_block<0, 2>(acc, a, b);

    // ---- P2: read a(g1)
#pragma unroll
    for (int ks = 0; ks < 2; ++ks)
#pragma unroll
      for (int i = 0; i < 4; ++i)
        a[i][ks] = *(const s16x8*)(As + aoff + 4096 + i * 1024 + kst[ks]);
    BARRIER(); WAIT_LGKM0();
    mfma_block<1, 0>(acc, a, b);

    // ---- P3: stage B(t+2) h0+h1 in-place (B reads retired < arrival B2;
    //          this write issues after passing B2)
    if (t + 2 < NT) {
      selB(t + 2, &p, &ko);
      stage_half(p, K, n0, ko, (u16*)Bs, tid);
      stage_half(p, K, n0 + 128, ko, (u16*)Bs + 128 * 64, tid);
    }
    BARRIER();
    // A(t+2)h0 in-place AFTER B3 (a(g1) reads retired < arrival B3)
    if (t + 2 < NT) {
      selA(t + 2, &p, &ko);
      stage_half(p, K, m0, ko, (u16*)As, tid);
    }
    mfma_block<1, 2>(acc, a, b);
    if (t < NT - 2) VMCNT(6);
    else if (t == NT - 2) VMCNT(0);
    BARRIER();
  }

#pragma unroll
  for (int fr = 0; fr < 8; ++fr) {
#pragma unroll
    for (int fc = 0; fc < 4; ++fc) {
      int gcol = n0 + wc * 64 + fc * 16 + (lane & 15);
      float bv = bias[gcol];
#pragma unroll
      for (int r = 0; r < 4; ++r) {
        int grow = m0 + wr * 128 + fr * 16 + (lane >> 4) * 4 + r;
        float v = acc[fr][fc][r] + bv;
        size_t o = (size_t)grow * N + gcol;
        if constexpr (EPI == 2) {
          Oh[o] = f2bf(sigm(v));
        } else {
          Of[o] = v;
        }
      }
    }
  }
}

// ===========================================================================
// gemm3s v4 (G1 + G2): stage-once 3-product 256^2, BK=32, single-barrier
// phases (proven r10). CHANGE: pass REORDER pass1(ah*bh) -> pass3(al*bh) ->
// pass2(ah*bl): b regs hold bh through ph0-ph3 (no ph re-read), bl ph4-5.
// LDS reads 36 -> 32 per wave per d-step, zero extra VGPR.
// Staging re-audited for new liveness (Ah now last-read at ph5):
//  - {Bh,Al,Ah}(d+1) -> other buf at ph0: other-buf last reads are (d-1)'s
//    ph0/ph3/ph5, each retired before arrival at the following barrier,
//    all < (d-1) end-barrier; writer passed it. SAFE.
//  - Bl(d+2) in-place issued AFTER B5 (ph4's Bl reads retired by
//    lgkm-after-B4 < arrival B5). SAFE.
// vmcnt: per d issues 6 (ph0) + 2 (ph5). End-of-d outstanding:
// Bl(d+1)[2] + 6 + Bl(d+2)[2] = 10 -> VMCNT(2) retires first 8.
// d >= ND-2 -> VMCNT(0). Accumulation order per acc: p1+p3+p2 (was p1+p2+p3)
// -> absmax not bit-identical, delta ~1e-6.
// EPI: 0 sigmoid->bf16 hi/lo; 4 fp32 partial at z*M*N (split-K, no bias)
// ===========================================================================
__device__ __forceinline__ void rd4(const u16* P, s16x8 (&v)[4]) {
#pragma unroll
  for (int i = 0; i < 4; ++i)
    v[i] = *(const s16x8*)(P + i * 512);  // 16 rows * 32 u16
}
template <int G>
__device__ __forceinline__ void mf16(f32x4 (&acc)[8][4], const s16x8 (&a)[4],
                                     const s16x8 (&b)[4]) {
  __builtin_amdgcn_s_setprio(1);
#pragma unroll
  for (int i = 0; i < 4; ++i)
#pragma unroll
    for (int j = 0; j < 4; ++j)
      acc[G * 4 + i][j] = __builtin_amdgcn_mfma_f32_16x16x32_bf16(
          a[i], b[j], acc[G * 4 + i][j], 0, 0, 0);
  __builtin_amdgcn_s_setprio(0);
}

template <int EPI>
__global__ __launch_bounds__(512, 2) void gemm3s_kernel(
    const u16* __restrict__ Ah, const u16* __restrict__ Al,
    const u16* __restrict__ Bh, const u16* __restrict__ Bl,
    const float* __restrict__ bias,
    float* __restrict__ Of, u16* __restrict__ Oh, u16* __restrict__ Ol,
    int M, int N, int K, int ldk) {
  __shared__ __attribute__((aligned(16))) u16 lds[2][4][256 * 32];
  constexpr int PAh = 0, PAl = 8192, PBh = 16384, PBl = 24576;

  const int tid = threadIdx.x;
  const int lane = tid & 63;
  const int wid = tid >> 6;
  const int wr = wid >> 2, wc = wid & 3;

  const int gx = gridDim.x, gy = gridDim.y;
  const int nwg = gx * gy * gridDim.z;
  int orig = ((int)blockIdx.z * gy + blockIdx.y) * gx + blockIdx.x;
  int swz = (orig & 7) * (nwg >> 3) + (orig >> 3);  // nwg % 8 == 0
  const int bx = swz % gx;
  int rem = swz / gx;
  const int by = rem % gy;
  const int bz = rem / gy;
  const int m0 = by * 256, n0 = bx * 256;
  const int kb = bz * K;
  const int ND = K >> 5;

  f32x4 acc[8][4];
#pragma unroll
  for (int i = 0; i < 8; ++i)
#pragma unroll
    for (int j = 0; j < 4; ++j) acc[i][j] = (f32x4){0.f, 0.f, 0.f, 0.f};

  const int pg8 = (((lane >> 4) ^ ((lane >> 1) & 3))) * 8;
  const int aof0 = (wr * 128 + (lane & 15)) * 32 + pg8;
  const int aof1 = aof0 + 2048;  // +64 rows
  const int bof = (wc * 64 + (lane & 15)) * 32 + pg8;

  const int sgl8 = ((tid & 3) ^ ((tid >> 3) & 3)) * 8;
  const size_t sso0 = (size_t)(tid >> 2) * ldk + sgl8;
  const size_t sso1 = sso0 + (size_t)128 * ldk;
  const int sdo0 = tid * 8, sdo1 = 4096 + tid * 8;
  const size_t aRow = (size_t)m0 * ldk;
  const size_t bRow = (size_t)n0 * ldk;

#define STAGEP(SRC, ROWB, KO, DST)                          \
  do {                                                      \
    gload_lds16((SRC) + (ROWB) + (size_t)(KO) + sso0, (DST) + sdo0); \
    gload_lds16((SRC) + (ROWB) + (size_t)(KO) + sso1, (DST) + sdo1); \
  } while (0)

  // prologue: buffer0 {Bh,Al,Ah,Bl}(0); buffer1 {Bl(1)}
  STAGEP(Bh, bRow, kb, &lds[0][0][PBh]);
  STAGEP(Al, aRow, kb, &lds[0][0][PAl]);
  STAGEP(Ah, aRow, kb, &lds[0][0][PAh]);
  STAGEP(Bl, bRow, kb, &lds[0][0][PBl]);
  if (ND > 1) {
    STAGEP(Bl, bRow, kb + 32, &lds[1][0][PBl]);
    VMCNT(2);  // buffer0 fully landed; Bl(1) in flight
  } else {
    VMCNT(0);
  }
  BARRIER();

  for (int d = 0; d < ND; ++d) {
    const int c = d & 1;
    const u16* Pc = &lds[c][0][0];
    u16* Po = &lds[c ^ 1][0][0];
    s16x8 a[4], b[4];
    const int kn1 = kb + (d + 1) * 32;
    const int kn2 = kb + (d + 2) * 32;

    // ph0: pass1 (Ah x Bh) g0; stage {Bh,Al,Ah}(d+1) -> other buf
    rd4(Pc + PAh + aof0, a);
    rd4(Pc + PBh + bof, b);
    if (d + 1 < ND) {
      STAGEP(Bh, bRow, kn1, Po + PBh);
      STAGEP(Al, aRow, kn1, Po + PAl);
      STAGEP(Ah, aRow, kn1, Po + PAh);
    }
    BARRIER(); WAIT_LGKM0();
    mf16<0>(acc, a, b);
    // ph1: pass1 g1 (bh held)
    rd4(Pc + PAh + aof1, a);
    BARRIER(); WAIT_LGKM0();
    mf16<1>(acc, a, b);
    // ph2: pass3 (Al x Bh) g0 — bh STILL held, no b read
    rd4(Pc + PAl + aof0, a);
    BARRIER(); WAIT_LGKM0();
    mf16<0>(acc, a, b);
    // ph3: pass3 g1
    rd4(Pc + PAl + aof1, a);
    BARRIER(); WAIT_LGKM0();
    mf16<1>(acc, a, b);
    // ph4: pass2 (Ah x Bl) g0 — re-read ah, read bl
    rd4(Pc + PAh + aof0, a);
    rd4(Pc + PBl + bof, b);
    BARRIER(); WAIT_LGKM0();
    mf16<0>(acc, a, b);
    // ph5: pass2 g1; stage Bl(d+2) in-place AFTER B5
    rd4(Pc + PAh + aof1, a);
    BARRIER(); WAIT_LGKM0();
    if (d + 2 < ND) STAGEP(Bl, bRow, kn2, (u16*)Pc + PBl);
    mf16<1>(acc, a, b);
    if (d < ND - 2) VMCNT(2);
    else VMCNT(0);
    BARRIER();
  }
#undef STAGEP

#pragma unroll
  for (int fr = 0; fr < 8; ++fr) {
#pragma unroll
    for (int fc = 0; fc < 4; ++fc) {
      int gcol = n0 + wc * 64 + fc * 16 + (lane & 15);
      float bv = (EPI == 4) ? 0.f : bias[gcol];
#pragma unroll
      for (int r = 0; r < 4; ++r) {
        int grow = m0 + wr * 128 + fr * 16 + (lane >> 4) * 4 + r;
        float v = acc[fr][fc][r] + bv;
        size_t o = (size_t)grow * N + gcol;
        if constexpr (EPI == 0) {
          v = sigm(v);
          u16 h = f2bf(v);
          Oh[o] = h;
          Ol[o] = f2bf(v - bf2f(h));
        } else {
          Of[(size_t)bz * M * N + o] = v;
        }
      }
    }
  }
}

// ===========================================================================
// Weight transpose/split, x split
// ===========================================================================
template <int SPLIT>
__global__ __launch_bounds__(256) void wsplitT_kernel(const float* __restrict__ W,
                                                      u16* __restrict__ Th,
                                                      u16* __restrict__ Tl,
                                                      int K, int N) {
  __shared__ float t[32][33];
  int bx = blockIdx.x * 32;
  int by = blockIdx.y * 32;
  int tx = threadIdx.x, ty = threadIdx.y;
  for (int i = ty; i < 32; i += 8) t[i][tx] = W[(size_t)(by + i) * N + bx + tx];
  __syncthreads();
  for (int i = ty; i < 32; i += 8) {
    float v = t[tx][i];
    size_t o = (size_t)(bx + i) * K + by + tx;
    u16 h = f2bf(v);
    Th[o] = h;
    if constexpr (SPLIT) Tl[o] = f2bf(v - bf2f(h));
  }
}

__global__ __launch_bounds__(256) void split_kernel(const float* __restrict__ X,
                                                    u16* __restrict__ Xh,
                                                    u16* __restrict__ Xl, size_t n) {
  size_t i = ((size_t)blockIdx.x * 256 + threadIdx.x) * 8;
  if (i >= n) return;
  float xs[8];
  *(float4*)(xs)     = *(const float4*)(X + i);
  *(float4*)(xs + 4) = *(const float4*)(X + i + 4);
  s16x8 hv, lv;
#pragma unroll
  for (int j = 0; j < 8; ++j) {
    u16 h = f2bf(xs[j]);
    hv[j] = (short)h;
    lv[j] = (short)f2bf(xs[j] - bf2f(h));
  }
  *(s16x8*)(Xh + i) = hv;
  *(s16x8*)(Xl + i) = lv;
}

// ===========================================================================
// Top-k mask; FUSED=1: input = sigm(pa + pb + bias) (split-K partials)
// ===========================================================================
__device__ __forceinline__ int blockScanIncl(int v, int tid, int* warpTmp) {
  __syncthreads();
  int lane = tid & 63, wid = tid >> 6;
#pragma unroll
  for (int o = 1; o < 64; o <<= 1) {
    int n = __shfl_up(v, o, 64);
    if (lane >= o) v += n;
  }
  if (lane == 63) warpTmp[wid] = v;
  __syncthreads();
  if (tid == 0) {
    int s = 0;
#pragma unroll
    for (int i = 0; i < 4; ++i) { int tt = warpTmp[i]; warpTmp[i] = s; s += tt; }
  }
  __syncthreads();
  return v + warpTmp[wid];
}

template <int FUSED>
__global__ __launch_bounds__(256) void topk_kernel(const float* __restrict__ pa,
                                                   const float* __restrict__ pb,
                                                   const float* __restrict__ bias,
                                                   u16* __restrict__ hm, int N, int k) {
  int row = blockIdx.x;
  int tid = threadIdx.x;
  __shared__ int hist[256];
  __shared__ int warpTmp[4];
  __shared__ int sh_digit, sh_rk;

  float4 va = reinterpret_cast<const float4*>(pa + (size_t)row * N)[tid];
  float fv[4];
  if constexpr (FUSED) {
    float4 vb = reinterpret_cast<const float4*>(pb + (size_t)row * N)[tid];
    float4 bb = reinterpret_cast<const float4*>(bias)[tid];
    fv[0] = sigm(va.x + vb.x + bb.x);
    fv[1] = sigm(va.y + vb.y + bb.y);
    fv[2] = sigm(va.z + vb.z + bb.z);
    fv[3] = sigm(va.w + vb.w + bb.w);
  } else {
    fv[0] = va.x; fv[1] = va.y; fv[2] = va.z; fv[3] = va.w;
  }
  u32 u[4];
#pragma unroll
  for (int s = 0; s < 4; ++s) u[s] = __float_as_uint(fv[s]);

  u32 pfx = 0;
  int rk = k;
#pragma unroll
  for (int p = 3; p >= 0; --p) {
    hist[tid] = 0;
    __syncthreads();
#pragma unroll
    for (int s = 0; s < 4; ++s) {
      bool cand = (p == 3) || ((u[s] >> ((p + 1) * 8)) == pfx);
      if (cand) atomicAdd(&hist[(u[s] >> (p * 8)) & 255], 1);
    }
    __syncthreads();
    int val = hist[255 - tid];
    int S = blockScanIncl(val, tid, warpTmp);
    if (S >= rk && (S - val) < rk) {
      sh_digit = 255 - tid;
      sh_rk = rk - (S - val);
    }
    __syncthreads();
    pfx = (pfx << 8) | (u32)sh_digit;
    rk = sh_rk;
    __syncthreads();
  }

  u32 t = pfx;
  int cnt = 0;
#pragma unroll
  for (int s = 0; s < 4; ++s) cnt += (u[s] == t) ? 1 : 0;
  int inc = blockScanIncl(cnt, tid, warpTmp);
  int r = inc - cnt;
  ushort4 o4;
  u16 ov[4];
#pragma unroll
  for (int s = 0; s < 4; ++s) {
    bool sel;
    if (u[s] > t) sel = true;
    else if (u[s] == t) { sel = (r < rk); ++r; }
    else sel = false;
    ov[s] = sel ? f2bf(fv[s]) : (u16)0;
  }
  o4.x = ov[0]; o4.y = ov[1]; o4.z = ov[2]; o4.w = ov[3];
  reinterpret_cast<ushort4*>(hm + (size_t)row * N)[tid] = o4;
}

// ===========================================================================
extern "C" void kernel_launch(void* const* d_in, const int* in_sizes, int n_in,
                              void* d_out, int out_size, void* d_ws, size_t ws_size,
                              hipStream_t stream) {
  (void)in_sizes; (void)n_in; (void)out_size;
  const float* x   = (const float*)d_in[0];
  const float* eW0 = (const float*)d_in[1];
  const float* eb0 = (const float*)d_in[2];
  const float* eW1 = (const float*)d_in[3];
  const float* eb1 = (const float*)d_in[4];
  const float* dW1 = (const float*)d_in[5];
  const float* db1 = (const float*)d_in[6];
  const float* dW0 = (const float*)d_in[7];
  const float* db0 = (const float*)d_in[8];
  float* out = (float*)d_out;

  const int B = 8192, D = 4096, H1 = 2048, H2 = 1024, KSEL = 51;

  auto pad = [](size_t b) { return (b + 255) & ~(size_t)255; };
  size_t szW0T  = pad((size_t)H1 * D * 2);
  size_t szW1T  = pad((size_t)H2 * H1 * 2);
  size_t szdW1T = pad((size_t)H1 * H2 * 2);
  size_t szdW0T = pad((size_t)D * H1 * 2);
  size_t szH1   = pad((size_t)B * H1 * 2);
  size_t szX    = pad((size_t)B * D * 2);
  size_t szP    = pad((size_t)B * H2 * 4);
  size_t szHM   = pad((size_t)B * H2 * 2);
  size_t szDD   = pad((size_t)B * H1 * 2);
  size_t persistent = 2 * szW0T + 2 * szW1T + szdW1T + szdW0T + 2 * szH1;
  size_t uniA = 2 * szX;
  size_t uniB = 2 * szP + szHM + szDD;
  size_t uni = (uniA > uniB) ? uniA : uniB;
  bool newpath = (persistent + uni) <= ws_size;

  dim3 tb(32, 8);

  if (newpath) {
    char* cur = (char*)d_ws;
    auto take = [&](size_t b) { char* r = cur; cur += b; return r; };
    u16* W0Th = (u16*)take(szW0T);
    u16* W0Tl = (u16*)take(szW0T);
    u16* W1Th = (u16*)take(szW1T);
    u16* W1Tl = (u16*)take(szW1T);
    u16* dW1T = (u16*)take(szdW1T);
    u16* dW0T = (u16*)take(szdW0T);
    u16* h1h  = (u16*)take(szH1);
    u16* h1l  = (u16*)take(szH1);
    char* u0  = take(uni);
    u16* xh = (u16*)u0;
    u16* xl = (u16*)(u0 + szX);
    float* p0 = (float*)u0;
    u16* hm = (u16*)(u0 + 2 * szP);
    u16* dd = (u16*)(u0 + 2 * szP + szHM);

    wsplitT_kernel<1><<<dim3(H1 / 32, D / 32), tb, 0, stream>>>(eW0, W0Th, W0Tl, D, H1);
    wsplitT_kernel<1><<<dim3(H2 / 32, H1 / 32), tb, 0, stream>>>(eW1, W1Th, W1Tl, H1, H2);
    wsplitT_kernel<0><<<dim3(H1 / 32, H2 / 32), tb, 0, stream>>>(dW1, dW1T, nullptr, H2, H1);
    wsplitT_kernel<0><<<dim3(D / 32, H1 / 32), tb, 0, stream>>>(dW0, dW0T, nullptr, H1, D);

    size_t n = (size_t)B * D;
    split_kernel<<<(unsigned)(n / (256 * 8)), 256, 0, stream>>>(x, xh, xl, n);

    // G1: stage-once 3-product 256^2, v4 (pass reorder, 32 reads/d)
    gemm3s_kernel<0><<<dim3(H1 / 256, B / 256, 1), 512, 0, stream>>>(
        xh, xl, W0Th, W0Tl, eb0, nullptr, h1h, h1l, B, H1, D, D);
    // G2: stage-once 3-product, split-K x2 -> fp32 partials
    gemm3s_kernel<4><<<dim3(H2 / 256, B / 256, 2), 512, 0, stream>>>(
        h1h, h1l, W1Th, W1Tl, nullptr, p0, nullptr, nullptr, B, H2, H1 / 2, H1);
    // top-k mask fused with partial-add + bias + sigmoid
    topk_kernel<1><<<B, 256, 0, stream>>>(p0, p0 + (size_t)B * H2, eb1, hm, H2, KSEL);
    // G3: plain bf16 gemm8p v2 (5-barrier)
    gemm8p_kernel<1, 2><<<dim3(H1 / 256, B / 256), 512, 0, stream>>>(
        hm, nullptr, dW1T, nullptr, db1, nullptr, dd, nullptr, B, H1, H2);
    // G4: plain bf16 gemm8p v2, fp32 out
    gemm8p_kernel<1, 3><<<dim3(D / 256, B / 256), 512, 0, stream>>>(
        dd, nullptr, dW0T, nullptr, db0, out, nullptr, nullptr, B, D, H1);
    return;
  }

  // ---------------- fallback: round-1 pipeline ----------------
  size_t off = 0;
  char* base = (char*)d_ws;
  auto alloc = [&](size_t bytes) -> char* {
    char* p2 = base + off;
    off += (bytes + 255) & ~(size_t)255;
    return p2;
  };
  u16* W0Th = (u16*)alloc((size_t)H1 * D * 2);
  u16* W0Tl = (u16*)alloc((size_t)H1 * D * 2);
  u16* W1Th = (u16*)alloc((size_t)H2 * H1 * 2);
  u16* W1Tl = (u16*)alloc((size_t)H2 * H1 * 2);
  u16* dW1T = (u16*)alloc((size_t)H1 * H2 * 2);
  u16* dW0T = (u16*)alloc((size_t)D * H1 * 2);
  u16* h1h  = (u16*)alloc((size_t)B * H1 * 2);
  u16* h1l  = (u16*)alloc((size_t)B * H1 * 2);
  float* h2 = (float*)alloc((size_t)B * H2 * 4);
  u16* hm   = (u16*)alloc((size_t)B * H2 * 2);
  u16* dd   = (u16*)alloc((size_t)B * H1 * 2);
  size_t need_x = 2 * (((size_t)B * D * 2 + 255) & ~(size_t)255);
  bool presplit = (off + need_x) <= ws_size;
  u16 *xh = nullptr, *xl = nullptr;
  if (presplit) {
    xh = (u16*)alloc((size_t)B * D * 2);
    xl = (u16*)alloc((size_t)B * D * 2);
  }

  wsplitT_kernel<1><<<dim3(H1 / 32, D / 32), tb, 0, stream>>>(eW0, W0Th, W0Tl, D, H1);
  wsplitT_kernel<1><<<dim3(H2 / 32, H1 / 32), tb, 0, stream>>>(eW1, W1Th, W1Tl, H1, H2);
  wsplitT_kernel<0><<<dim3(H1 / 32, H2 / 32), tb, 0, stream>>>(dW1, dW1T, nullptr, H2, H1);
  wsplitT_kernel<0><<<dim3(D / 32, H1 / 32), tb, 0, stream>>>(dW0, dW0T, nullptr, H1, D);

  if (presplit) {
    size_t n = (size_t)B * D;
    split_kernel<<<(unsigned)(n / (256 * 8)), 256, 0, stream>>>(x, xh, xl, n);
    gemm_kernel<1, 1, 0><<<dim3(H1 / 128, B / 128), 256, 0, stream>>>(
        nullptr, xh, xl, W0Th, W0Tl, eb0, nullptr, h1h, h1l, B, H1, D);
  } else {
    gemm_kernel<0, 1, 0><<<dim3(H1 / 128, B / 128), 256, 0, stream>>>(
        x, nullptr, nullptr, W0Th, W0Tl, eb0, nullptr, h1h, h1l, B, H1, D);
  }
  gemm_kernel<1, 1, 1><<<dim3(H2 / 128, B / 128), 256, 0, stream>>>(
      nullptr, h1h, h1l, W1Th, W1Tl, eb1, h2, nullptr, nullptr, B, H2, H1);
  topk_kernel<0><<<B, 256, 0, stream>>>(h2, nullptr, nullptr, hm, H2, KSEL);
  gemm_kernel<2, 0, 2><<<dim3(H1 / 128, B / 128), 256, 0, stream>>>(
      nullptr, hm, nullptr, dW1T, nullptr, db1, nullptr, dd, nullptr, B, H1, H2);
  gemm_kernel<2, 0, 3><<<dim3(D / 128, B / 128), 256, 0, stream>>>(
      nullptr, dd, nullptr, dW0T, nullptr, db0, out, nullptr, nullptr, B, D, H1);
}

// Round 12
// 696.556 us; speedup vs baseline: 1.0258x; 1.0258x over previous
//
#include <hip/hip_runtime.h>

typedef unsigned short u16;
typedef unsigned int u32;
typedef float f32x4 __attribute__((ext_vector_type(4)));
typedef short s16x8 __attribute__((ext_vector_type(8)));

__device__ __forceinline__ u16 f2bf(float v) {
  union { float f; u32 u; } c; c.f = v;
  u32 r = c.u + 0x7FFFu + ((c.u >> 16) & 1u);
  return (u16)(r >> 16);
}
__device__ __forceinline__ float bf2f(u16 h) {
  union { u32 u; float f; } c; c.u = ((u32)h) << 16;
  return c.f;
}
__device__ __forceinline__ float sigm(float x) { return 1.0f / (1.0f + expf(-x)); }

__device__ __forceinline__ void gload_lds16(const void* g, void* l) {
  __builtin_amdgcn_global_load_lds(
      (const __attribute__((address_space(1))) void*)g,
      (__attribute__((address_space(3))) void*)l, 16, 0, 0);
}

#define BARRIER() asm volatile("s_barrier" ::: "memory")
#define WAIT_LGKM0() asm volatile("s_waitcnt lgkmcnt(0)" ::: "memory")
#define VMCNT(n) asm volatile("s_waitcnt vmcnt(" #n ")" ::: "memory")

// ===========================================================================
// OLD 128x128 kernel (round-1, known good) — fallback path only.
// ===========================================================================
__device__ __forceinline__ void stage_tile(const u16* __restrict__ G, int ld,
                                           int row0, int k0, u16* buf, int tid) {
#pragma unroll
  for (int r = 0; r < 2; ++r) {
    int ci = r * 256 + tid;
    int row = ci >> 2;
    int c = (ci & 3) * 8;
    gload_lds16(G + (size_t)(row0 + row) * ld + k0 + c, buf + (size_t)ci * 8);
  }
}

template <int ASRC, int BSPL, int EPI>
__global__ __launch_bounds__(256) void gemm_kernel(
    const float* __restrict__ Af, const u16* __restrict__ Ah, const u16* __restrict__ Al,
    const u16* __restrict__ Bh, const u16* __restrict__ Bl,
    const float* __restrict__ bias,
    float* __restrict__ Of, u16* __restrict__ Oh, u16* __restrict__ Ol,
    int M, int N, int K) {
  constexpr int BM = 128, BN = 128, BK = 32;
  constexpr bool SPLIT = (ASRC != 2) && (BSPL != 0);
  __shared__ __attribute__((aligned(16))) u16 Ahs[BM * BK];
  __shared__ __attribute__((aligned(16))) u16 Bhs[BN * BK];
  __shared__ __attribute__((aligned(16))) u16 Als[(ASRC != 2) ? BM * BK : 8];
  __shared__ __attribute__((aligned(16))) u16 Bls[BSPL ? BN * BK : 8];

  const int tid = threadIdx.x;
  const int lane = tid & 63;
  const int wid = tid >> 6;
  const int m0 = blockIdx.y * BM;
  const int n0 = blockIdx.x * BN;
  const int wm = (wid >> 1) * 64;
  const int wn = (wid & 1) * 64;

  f32x4 acc[4][4];
#pragma unroll
  for (int i = 0; i < 4; ++i)
#pragma unroll
    for (int j = 0; j < 4; ++j) acc[i][j] = (f32x4){0.f, 0.f, 0.f, 0.f};

  const int arow = lane & 15;
  const int asel = (lane >> 4) * 8;

  for (int k0 = 0; k0 < K; k0 += BK) {
    if constexpr (ASRC == 0) {
      int row = tid >> 1, cb = (tid & 1) << 4;
      const float* s = Af + (size_t)(m0 + row) * K + k0 + cb;
      float xs[16];
      *(float4*)(xs + 0)  = *(const float4*)(s + 0);
      *(float4*)(xs + 4)  = *(const float4*)(s + 4);
      *(float4*)(xs + 8)  = *(const float4*)(s + 8);
      *(float4*)(xs + 12) = *(const float4*)(s + 12);
      s16x8 hv[2], lv[2];
#pragma unroll
      for (int q = 0; q < 2; ++q)
#pragma unroll
        for (int i = 0; i < 8; ++i) {
          float xv = xs[q * 8 + i];
          u16 h = f2bf(xv);
          hv[q][i] = (short)h;
          lv[q][i] = (short)f2bf(xv - bf2f(h));
        }
      *(s16x8*)(&Ahs[row * BK + cb])     = hv[0];
      *(s16x8*)(&Ahs[row * BK + cb + 8]) = hv[1];
      *(s16x8*)(&Als[row * BK + cb])     = lv[0];
      *(s16x8*)(&Als[row * BK + cb + 8]) = lv[1];
    } else if constexpr (ASRC == 1) {
      stage_tile(Ah, K, m0, k0, Ahs, tid);
      stage_tile(Al, K, m0, k0, Als, tid);
    } else {
      stage_tile(Ah, K, m0, k0, Ahs, tid);
    }
    stage_tile(Bh, K, n0, k0, Bhs, tid);
    if constexpr (BSPL) stage_tile(Bl, K, n0, k0, Bls, tid);
    __syncthreads();

    s16x8 a_h[4], b_h[4];
    s16x8 a_l[4], b_l[4];
#pragma unroll
    for (int i = 0; i < 4; ++i) {
      a_h[i] = *(const s16x8*)(&Ahs[(wm + i * 16 + arow) * BK + asel]);
      b_h[i] = *(const s16x8*)(&Bhs[(wn + i * 16 + arow) * BK + asel]);
      if constexpr (SPLIT) {
        a_l[i] = *(const s16x8*)(&Als[(wm + i * 16 + arow) * BK + asel]);
        b_l[i] = *(const s16x8*)(&Bls[(wn + i * 16 + arow) * BK + asel]);
      }
    }
#pragma unroll
    for (int mi = 0; mi < 4; ++mi)
#pragma unroll
      for (int ni = 0; ni < 4; ++ni) {
        f32x4 c = acc[mi][ni];
        c = __builtin_amdgcn_mfma_f32_16x16x32_bf16(a_h[mi], b_h[ni], c, 0, 0, 0);
        if constexpr (SPLIT) {
          c = __builtin_amdgcn_mfma_f32_16x16x32_bf16(a_h[mi], b_l[ni], c, 0, 0, 0);
          c = __builtin_amdgcn_mfma_f32_16x16x32_bf16(a_l[mi], b_h[ni], c, 0, 0, 0);
        }
        acc[mi][ni] = c;
      }
    __syncthreads();
  }

#pragma unroll
  for (int mi = 0; mi < 4; ++mi) {
#pragma unroll
    for (int ni = 0; ni < 4; ++ni) {
      int gcol = n0 + wn + ni * 16 + (lane & 15);
      float bv = bias[gcol];
#pragma unroll
      for (int r = 0; r < 4; ++r) {
        int grow = m0 + wm + mi * 16 + (lane >> 4) * 4 + r;
        float v = acc[mi][ni][r] + bv;
        size_t o = (size_t)grow * N + gcol;
        if constexpr (EPI == 0) {
          v = sigm(v);
          u16 h = f2bf(v);
          Oh[o] = h;
          Ol[o] = f2bf(v - bf2f(h));
        } else if constexpr (EPI == 1) {
          Of[o] = sigm(v);
        } else if constexpr (EPI == 2) {
          Oh[o] = f2bf(sigm(v));
        } else {
          Of[o] = v;
        }
      }
    }
  }
}

// ===========================================================================
// gemm8p v2 (G3/G4): 5-barrier rhythm (KEPT from round 11 — arithmetic
// attribution says it improved G3+G4 by ~17 us; this round isolates it).
// ===========================================================================
__device__ __forceinline__ void stage_half(const u16* __restrict__ G, int ldk,
                                           int row0, int koff, u16* dst, int tid) {
#pragma unroll
  for (int r = 0; r < 2; ++r) {
    int ci = r * 512 + tid;            // 16B chunk, 0..1023 (128 rows x 64 cols)
    int rw = ci >> 3;                  // physical LDS row
    int gl = (ci & 7) ^ (rw & 7);      // inverse-swizzled source granule
    gload_lds16(G + (size_t)(row0 + rw) * ldk + koff + gl * 8, dst + ci * 8);
  }
}

template <int G, int J0>
__device__ __forceinline__ void mfma_block(f32x4 (&acc)[8][4],
                                           const s16x8 (&a)[4][2],
                                           const s16x8 (&b)[4][2]) {
  __builtin_amdgcn_s_setprio(1);
#pragma unroll
  for (int j = 0; j < 2; ++j)
#pragma unroll
    for (int i = 0; i < 4; ++i)
#pragma unroll
      for (int ks = 0; ks < 2; ++ks)
        acc[G * 4 + i][J0 + j] = __builtin_amdgcn_mfma_f32_16x16x32_bf16(
            a[i][ks], b[J0 + j][ks], acc[G * 4 + i][J0 + j], 0, 0, 0);
  __builtin_amdgcn_s_setprio(0);
}

// EPI: 2 sigmoid->bf16, 3 linear->fp32
template <int STREAMS, int EPI>
__global__ __launch_bounds__(512, 2) void gemm8p_kernel(
    const u16* __restrict__ Ah, const u16* __restrict__ Al,
    const u16* __restrict__ Bh, const u16* __restrict__ Bl,
    const float* __restrict__ bias,
    float* __restrict__ Of, u16* __restrict__ Oh, u16* __restrict__ Ol,
    int M, int N, int K) {
  __shared__ __attribute__((aligned(16))) u16 lds[2][2][256 * 64];  // 128 KiB
  const int tid = threadIdx.x;
  const int lane = tid & 63;
  const int wid = tid >> 6;
  const int wr = wid >> 2, wc = wid & 3;  // 2M x 4N wave grid

  const int gx = gridDim.x;
  int nwg = gx * gridDim.y;
  int orig = blockIdx.y * gx + blockIdx.x;
  int swz = (orig & 7) * (nwg >> 3) + (orig >> 3);  // nwg % 8 == 0 (bijective)
  int bx = swz % gx, by = swz / gx;
  const int m0 = by * 256, n0 = bx * 256;

  const int NT = (STREAMS == 3) ? 3 * (K >> 6) : (K >> 6);

  f32x4 acc[8][4];
#pragma unroll
  for (int i = 0; i < 8; ++i)
#pragma unroll
    for (int j = 0; j < 4; ++j) acc[i][j] = (f32x4){0.f, 0.f, 0.f, 0.f};

  const int aoff = (wr * 128 + (lane & 15)) * 64;
  const int boff = (wc * 64 + (lane & 15)) * 64;
  int kst[2];
#pragma unroll
  for (int ks = 0; ks < 2; ++ks)
    kst[ks] = ((ks * 4 + (lane >> 4)) ^ (lane & 7)) * 8;

  const u16* p; int ko;
  auto selA = [&](int s, const u16** pp, int* o) {
    if constexpr (STREAMS == 3) {
      int d = s / 3, r = s - d * 3;
      *pp = (r == 2) ? Al : Ah;
      *o = d << 6;
    } else { *pp = Ah; *o = s << 6; }
  };
  auto selB = [&](int s, const u16** pp, int* o) {
    if constexpr (STREAMS == 3) {
      int d = s / 3, r = s - d * 3;
      *pp = (r == 1) ? Bl : Bh;
      *o = d << 6;
    } else { *pp = Bh; *o = s << 6; }
  };

  // prologue: K0 {Bh0,Bh1,Ah0,Ah1} -> buf0 ; K1 {Bh0,Bh1,Ah0} -> buf1
  selB(0, &p, &ko);
  stage_half(p, K, n0, ko, &lds[0][1][0], tid);
  stage_half(p, K, n0 + 128, ko, &lds[0][1][128 * 64], tid);
  selA(0, &p, &ko);
  stage_half(p, K, m0, ko, &lds[0][0][0], tid);
  stage_half(p, K, m0 + 128, ko, &lds[0][0][128 * 64], tid);
  selB(1, &p, &ko);
  stage_half(p, K, n0, ko, &lds[1][1][0], tid);
  stage_half(p, K, n0 + 128, ko, &lds[1][1][128 * 64], tid);
  selA(1, &p, &ko);
  stage_half(p, K, m0, ko, &lds[1][0][0], tid);
  VMCNT(6);  // K0 fully landed
  BARRIER();

  for (int t = 0; t < NT; ++t) {
    const int bt = t & 1;
    const u16* As = &lds[bt][0][0];
    const u16* Bs = &lds[bt][1][0];
    u16* Adst_n = &lds[bt ^ 1][0][0];
    s16x8 a[4][2], b[4][2];

    // ---- P0: read a(g0), b(cols 0,1); stage A(t+1)h1 (other buffer)
#pragma unroll
    for (int ks = 0; ks < 2; ++ks) {
#pragma unroll
      for (int i = 0; i < 4; ++i)
        a[i][ks] = *(const s16x8*)(As + aoff + i * 1024 + kst[ks]);
#pragma unroll
      for (int j = 0; j < 2; ++j)
        b[j][ks] = *(const s16x8*)(Bs + boff + j * 1024 + kst[ks]);
    }
    if (t + 1 < NT) {
      selA(t + 1, &p, &ko);
      stage_half(p, K, m0 + 128, ko, Adst_n + 128 * 64, tid);
    }
    BARRIER(); WAIT_LGKM0();
    mfma_block<0, 0>(acc, a, b);

    // ---- P1: read b(cols 2,3)
#pragma unroll
    for (int ks = 0; ks < 2; ++ks)
#pragma unroll
      for (int j = 2; j < 4; ++j)
        b[j][ks] = *(const s16x8*)(Bs + boff + j * 1024 + kst[ks]);
    BARRIER(); WAIT_LGKM0();
    mfma_block<0, 2>(acc, a, b);

    // ---- P2: read a(g1)
#pragma unroll
    for (int ks = 0; ks < 2; ++ks)
#pragma unroll
      for (int i = 0; i < 4; ++i)
        a[i][ks] = *(const s16x8*)(As + aoff + 4096 + i * 1024 + kst[ks]);
    BARRIER(); WAIT_LGKM0();
    mfma_block<1, 0>(acc, a, b);

    // ---- P3: stage B(t+2) h0+h1 in-place (B reads retired < arrival B2;
    //          this write issues after passing B2)
    if (t + 2 < NT) {
      selB(t + 2, &p, &ko);
      stage_half(p, K, n0, ko, (u16*)Bs, tid);
      stage_half(p, K, n0 + 128, ko, (u16*)Bs + 128 * 64, tid);
    }
    BARRIER();
    // A(t+2)h0 in-place AFTER B3 (a(g1) reads retired < arrival B3)
    if (t + 2 < NT) {
      selA(t + 2, &p, &ko);
      stage_half(p, K, m0, ko, (u16*)As, tid);
    }
    mfma_block<1, 2>(acc, a, b);
    if (t < NT - 2) VMCNT(6);
    else if (t == NT - 2) VMCNT(0);
    BARRIER();
  }

#pragma unroll
  for (int fr = 0; fr < 8; ++fr) {
#pragma unroll
    for (int fc = 0; fc < 4; ++fc) {
      int gcol = n0 + wc * 64 + fc * 16 + (lane & 15);
      float bv = bias[gcol];
#pragma unroll
      for (int r = 0; r < 4; ++r) {
        int grow = m0 + wr * 128 + fr * 16 + (lane >> 4) * 4 + r;
        float v = acc[fr][fc][r] + bv;
        size_t o = (size_t)grow * N + gcol;
        if constexpr (EPI == 2) {
          Oh[o] = f2bf(sigm(v));
        } else {
          Of[o] = v;
        }
      }
    }
  }
}

// ===========================================================================
// gemm3s v3 (G1 + G2): EXACT round-10 revert — stage-once 3-product 256^2,
// BK=32, single-barrier phases, original pass order 1,2,3, staging spread
// across ph0/ph1/ph4/ph5 (phase-balanced; v4's concentrated staging at ph0
// regressed 333->361: in a skew-overlapped rhythm phase BALANCE beats total
// read count). VMCNT(4) steady, d<ND-2 cutoff. Proven 333 us / 58.4%.
// EPI: 0 sigmoid->bf16 hi/lo; 4 fp32 partial at z*M*N (split-K, no bias)
// ===========================================================================
__device__ __forceinline__ void rd4(const u16* P, s16x8 (&v)[4]) {
#pragma unroll
  for (int i = 0; i < 4; ++i)
    v[i] = *(const s16x8*)(P + i * 512);  // 16 rows * 32 u16
}
template <int G>
__device__ __forceinline__ void mf16(f32x4 (&acc)[8][4], const s16x8 (&a)[4],
                                     const s16x8 (&b)[4]) {
  __builtin_amdgcn_s_setprio(1);
#pragma unroll
  for (int i = 0; i < 4; ++i)
#pragma unroll
    for (int j = 0; j < 4; ++j)
      acc[G * 4 + i][j] = __builtin_amdgcn_mfma_f32_16x16x32_bf16(
          a[i], b[j], acc[G * 4 + i][j], 0, 0, 0);
  __builtin_amdgcn_s_setprio(0);
}

template <int EPI>
__global__ __launch_bounds__(512, 2) void gemm3s_kernel(
    const u16* __restrict__ Ah, const u16* __restrict__ Al,
    const u16* __restrict__ Bh, const u16* __restrict__ Bl,
    const float* __restrict__ bias,
    float* __restrict__ Of, u16* __restrict__ Oh, u16* __restrict__ Ol,
    int M, int N, int K, int ldk) {
  __shared__ __attribute__((aligned(16))) u16 lds[2][4][256 * 32];
  constexpr int PAh = 0, PAl = 8192, PBh = 16384, PBl = 24576;

  const int tid = threadIdx.x;
  const int lane = tid & 63;
  const int wid = tid >> 6;
  const int wr = wid >> 2, wc = wid & 3;

  const int gx = gridDim.x, gy = gridDim.y;
  const int nwg = gx * gy * gridDim.z;
  int orig = ((int)blockIdx.z * gy + blockIdx.y) * gx + blockIdx.x;
  int swz = (orig & 7) * (nwg >> 3) + (orig >> 3);  // nwg % 8 == 0
  const int bx = swz % gx;
  int rem = swz / gx;
  const int by = rem % gy;
  const int bz = rem / gy;
  const int m0 = by * 256, n0 = bx * 256;
  const int kb = bz * K;
  const int ND = K >> 5;

  f32x4 acc[8][4];
#pragma unroll
  for (int i = 0; i < 8; ++i)
#pragma unroll
    for (int j = 0; j < 4; ++j) acc[i][j] = (f32x4){0.f, 0.f, 0.f, 0.f};

  const int pg8 = (((lane >> 4) ^ ((lane >> 1) & 3))) * 8;
  const int aof0 = (wr * 128 + (lane & 15)) * 32 + pg8;
  const int aof1 = aof0 + 2048;  // +64 rows
  const int bof = (wc * 64 + (lane & 15)) * 32 + pg8;

  const int sgl8 = ((tid & 3) ^ ((tid >> 3) & 3)) * 8;
  const size_t sso0 = (size_t)(tid >> 2) * ldk + sgl8;
  const size_t sso1 = sso0 + (size_t)128 * ldk;
  const int sdo0 = tid * 8, sdo1 = 4096 + tid * 8;
  const size_t aRow = (size_t)m0 * ldk;
  const size_t bRow = (size_t)n0 * ldk;

#define STAGEP(SRC, ROWB, KO, DST)                          \
  do {                                                      \
    gload_lds16((SRC) + (ROWB) + (size_t)(KO) + sso0, (DST) + sdo0); \
    gload_lds16((SRC) + (ROWB) + (size_t)(KO) + sso1, (DST) + sdo1); \
  } while (0)

  STAGEP(Bh, bRow, kb, &lds[0][0][PBh]);
  STAGEP(Al, aRow, kb, &lds[0][0][PAl]);
  STAGEP(Bl, bRow, kb, &lds[0][0][PBl]);
  STAGEP(Ah, aRow, kb, &lds[0][0][PAh]);
  if (ND > 1) {
    STAGEP(Bl, bRow, kb + 32, &lds[1][0][PBl]);
    STAGEP(Ah, aRow, kb + 32, &lds[1][0][PAh]);
    VMCNT(4);
  } else {
    VMCNT(0);
  }
  BARRIER();

  for (int d = 0; d < ND; ++d) {
    const int c = d & 1;
    const u16* Pc = &lds[c][0][0];
    u16* Po = &lds[c ^ 1][0][0];
    s16x8 a[4], b[4];
    const int kn1 = kb + (d + 1) * 32;
    const int kn2 = kb + (d + 2) * 32;

    // ph0: pass1 (Ah x Bh) g0; stage Bh(d+1) -> other buf
    rd4(Pc + PAh + aof0, a);
    rd4(Pc + PBh + bof, b);
    if (d + 1 < ND) STAGEP(Bh, bRow, kn1, Po + PBh);
    BARRIER(); WAIT_LGKM0();
    mf16<0>(acc, a, b);
    // ph1: pass1 g1; stage Al(d+1) -> other buf
    rd4(Pc + PAh + aof1, a);
    if (d + 1 < ND) STAGEP(Al, aRow, kn1, Po + PAl);
    BARRIER(); WAIT_LGKM0();
    mf16<1>(acc, a, b);
    // ph2: pass2 (Ah x Bl) g0
    rd4(Pc + PAh + aof0, a);
    rd4(Pc + PBl + bof, b);
    BARRIER(); WAIT_LGKM0();
    mf16<0>(acc, a, b);
    // ph3: pass2 g1
    rd4(Pc + PAh + aof1, a);
    BARRIER(); WAIT_LGKM0();
    mf16<1>(acc, a, b);
    // ph4: pass3 (Al x Bh) g0; stage Bl(d+2) in-place (PBl last read ph2)
    rd4(Pc + PAl + aof0, a);
    rd4(Pc + PBh + bof, b);
    if (d + 2 < ND) STAGEP(Bl, bRow, kn2, (u16*)Pc + PBl);
    BARRIER(); WAIT_LGKM0();
    mf16<0>(acc, a, b);
    // ph5: pass3 g1; stage Ah(d+2) in-place (PAh last read ph3)
    rd4(Pc + PAl + aof1, a);
    if (d + 2 < ND) STAGEP(Ah, aRow, kn2, (u16*)Pc + PAh);
    BARRIER(); WAIT_LGKM0();
    mf16<1>(acc, a, b);
    if (d < ND - 2) VMCNT(4);
    else VMCNT(0);
    BARRIER();
  }
#undef STAGEP

#pragma unroll
  for (int fr = 0; fr < 8; ++fr) {
#pragma unroll
    for (int fc = 0; fc < 4; ++fc) {
      int gcol = n0 + wc * 64 + fc * 16 + (lane & 15);
      float bv = (EPI == 4) ? 0.f : bias[gcol];
#pragma unroll
      for (int r = 0; r < 4; ++r) {
        int grow = m0 + wr * 128 + fr * 16 + (lane >> 4) * 4 + r;
        float v = acc[fr][fc][r] + bv;
        size_t o = (size_t)grow * N + gcol;
        if constexpr (EPI == 0) {
          v = sigm(v);
          u16 h = f2bf(v);
          Oh[o] = h;
          Ol[o] = f2bf(v - bf2f(h));
        } else {
          Of[(size_t)bz * M * N + o] = v;
        }
      }
    }
  }
}

// ===========================================================================
// Weight transpose/split, x split
// ===========================================================================
template <int SPLIT>
__global__ __launch_bounds__(256) void wsplitT_kernel(const float* __restrict__ W,
                                                      u16* __restrict__ Th,
                                                      u16* __restrict__ Tl,
                                                      int K, int N) {
  __shared__ float t[32][33];
  int bx = blockIdx.x * 32;
  int by = blockIdx.y * 32;
  int tx = threadIdx.x, ty = threadIdx.y;
  for (int i = ty; i < 32; i += 8) t[i][tx] = W[(size_t)(by + i) * N + bx + tx];
  __syncthreads();
  for (int i = ty; i < 32; i += 8) {
    float v = t[tx][i];
    size_t o = (size_t)(bx + i) * K + by + tx;
    u16 h = f2bf(v);
    Th[o] = h;
    if constexpr (SPLIT) Tl[o] = f2bf(v - bf2f(h));
  }
}

__global__ __launch_bounds__(256) void split_kernel(const float* __restrict__ X,
                                                    u16* __restrict__ Xh,
                                                    u16* __restrict__ Xl, size_t n) {
  size_t i = ((size_t)blockIdx.x * 256 + threadIdx.x) * 8;
  if (i >= n) return;
  float xs[8];
  *(float4*)(xs)     = *(const float4*)(X + i);
  *(float4*)(xs + 4) = *(const float4*)(X + i + 4);
  s16x8 hv, lv;
#pragma unroll
  for (int j = 0; j < 8; ++j) {
    u16 h = f2bf(xs[j]);
    hv[j] = (short)h;
    lv[j] = (short)f2bf(xs[j] - bf2f(h));
  }
  *(s16x8*)(Xh + i) = hv;
  *(s16x8*)(Xl + i) = lv;
}

// ===========================================================================
// Top-k mask; FUSED=1: input = sigm(pa + pb + bias) (split-K partials)
// ===========================================================================
__device__ __forceinline__ int blockScanIncl(int v, int tid, int* warpTmp) {
  __syncthreads();
  int lane = tid & 63, wid = tid >> 6;
#pragma unroll
  for (int o = 1; o < 64; o <<= 1) {
    int n = __shfl_up(v, o, 64);
    if (lane >= o) v += n;
  }
  if (lane == 63) warpTmp[wid] = v;
  __syncthreads();
  if (tid == 0) {
    int s = 0;
#pragma unroll
    for (int i = 0; i < 4; ++i) { int tt = warpTmp[i]; warpTmp[i] = s; s += tt; }
  }
  __syncthreads();
  return v + warpTmp[wid];
}

template <int FUSED>
__global__ __launch_bounds__(256) void topk_kernel(const float* __restrict__ pa,
                                                   const float* __restrict__ pb,
                                                   const float* __restrict__ bias,
                                                   u16* __restrict__ hm, int N, int k) {
  int row = blockIdx.x;
  int tid = threadIdx.x;
  __shared__ int hist[256];
  __shared__ int warpTmp[4];
  __shared__ int sh_digit, sh_rk;

  float4 va = reinterpret_cast<const float4*>(pa + (size_t)row * N)[tid];
  float fv[4];
  if constexpr (FUSED) {
    float4 vb = reinterpret_cast<const float4*>(pb + (size_t)row * N)[tid];
    float4 bb = reinterpret_cast<const float4*>(bias)[tid];
    fv[0] = sigm(va.x + vb.x + bb.x);
    fv[1] = sigm(va.y + vb.y + bb.y);
    fv[2] = sigm(va.z + vb.z + bb.z);
    fv[3] = sigm(va.w + vb.w + bb.w);
  } else {
    fv[0] = va.x; fv[1] = va.y; fv[2] = va.z; fv[3] = va.w;
  }
  u32 u[4];
#pragma unroll
  for (int s = 0; s < 4; ++s) u[s] = __float_as_uint(fv[s]);

  u32 pfx = 0;
  int rk = k;
#pragma unroll
  for (int p = 3; p >= 0; --p) {
    hist[tid] = 0;
    __syncthreads();
#pragma unroll
    for (int s = 0; s < 4; ++s) {
      bool cand = (p == 3) || ((u[s] >> ((p + 1) * 8)) == pfx);
      if (cand) atomicAdd(&hist[(u[s] >> (p * 8)) & 255], 1);
    }
    __syncthreads();
    int val = hist[255 - tid];
    int S = blockScanIncl(val, tid, warpTmp);
    if (S >= rk && (S - val) < rk) {
      sh_digit = 255 - tid;
      sh_rk = rk - (S - val);
    }
    __syncthreads();
    pfx = (pfx << 8) | (u32)sh_digit;
    rk = sh_rk;
    __syncthreads();
  }

  u32 t = pfx;
  int cnt = 0;
#pragma unroll
  for (int s = 0; s < 4; ++s) cnt += (u[s] == t) ? 1 : 0;
  int inc = blockScanIncl(cnt, tid, warpTmp);
  int r = inc - cnt;
  ushort4 o4;
  u16 ov[4];
#pragma unroll
  for (int s = 0; s < 4; ++s) {
    bool sel;
    if (u[s] > t) sel = true;
    else if (u[s] == t) { sel = (r < rk); ++r; }
    else sel = false;
    ov[s] = sel ? f2bf(fv[s]) : (u16)0;
  }
  o4.x = ov[0]; o4.y = ov[1]; o4.z = ov[2]; o4.w = ov[3];
  reinterpret_cast<ushort4*>(hm + (size_t)row * N)[tid] = o4;
}

// ===========================================================================
extern "C" void kernel_launch(void* const* d_in, const int* in_sizes, int n_in,
                              void* d_out, int out_size, void* d_ws, size_t ws_size,
                              hipStream_t stream) {
  (void)in_sizes; (void)n_in; (void)out_size;
  const float* x   = (const float*)d_in[0];
  const float* eW0 = (const float*)d_in[1];
  const float* eb0 = (const float*)d_in[2];
  const float* eW1 = (const float*)d_in[3];
  const float* eb1 = (const float*)d_in[4];
  const float* dW1 = (const float*)d_in[5];
  const float* db1 = (const float*)d_in[6];
  const float* dW0 = (const float*)d_in[7];
  const float* db0 = (const float*)d_in[8];
  float* out = (float*)d_out;

  const int B = 8192, D = 4096, H1 = 2048, H2 = 1024, KSEL = 51;

  auto pad = [](size_t b) { return (b + 255) & ~(size_t)255; };
  size_t szW0T  = pad((size_t)H1 * D * 2);
  size_t szW1T  = pad((size_t)H2 * H1 * 2);
  size_t szdW1T = pad((size_t)H1 * H2 * 2);
  size_t szdW0T = pad((size_t)D * H1 * 2);
  size_t szH1   = pad((size_t)B * H1 * 2);
  size_t szX    = pad((size_t)B * D * 2);
  size_t szP    = pad((size_t)B * H2 * 4);
  size_t szHM   = pad((size_t)B * H2 * 2);
  size_t szDD   = pad((size_t)B * H1 * 2);
  size_t persistent = 2 * szW0T + 2 * szW1T + szdW1T + szdW0T + 2 * szH1;
  size_t uniA = 2 * szX;
  size_t uniB = 2 * szP + szHM + szDD;
  size_t uni = (uniA > uniB) ? uniA : uniB;
  bool newpath = (persistent + uni) <= ws_size;

  dim3 tb(32, 8);

  if (newpath) {
    char* cur = (char*)d_ws;
    auto take = [&](size_t b) { char* r = cur; cur += b; return r; };
    u16* W0Th = (u16*)take(szW0T);
    u16* W0Tl = (u16*)take(szW0T);
    u16* W1Th = (u16*)take(szW1T);
    u16* W1Tl = (u16*)take(szW1T);
    u16* dW1T = (u16*)take(szdW1T);
    u16* dW0T = (u16*)take(szdW0T);
    u16* h1h  = (u16*)take(szH1);
    u16* h1l  = (u16*)take(szH1);
    char* u0  = take(uni);
    u16* xh = (u16*)u0;
    u16* xl = (u16*)(u0 + szX);
    float* p0 = (float*)u0;
    u16* hm = (u16*)(u0 + 2 * szP);
    u16* dd = (u16*)(u0 + 2 * szP + szHM);

    wsplitT_kernel<1><<<dim3(H1 / 32, D / 32), tb, 0, stream>>>(eW0, W0Th, W0Tl, D, H1);
    wsplitT_kernel<1><<<dim3(H2 / 32, H1 / 32), tb, 0, stream>>>(eW1, W1Th, W1Tl, H1, H2);
    wsplitT_kernel<0><<<dim3(H1 / 32, H2 / 32), tb, 0, stream>>>(dW1, dW1T, nullptr, H2, H1);
    wsplitT_kernel<0><<<dim3(D / 32, H1 / 32), tb, 0, stream>>>(dW0, dW0T, nullptr, H1, D);

    size_t n = (size_t)B * D;
    split_kernel<<<(unsigned)(n / (256 * 8)), 256, 0, stream>>>(x, xh, xl, n);

    // G1: stage-once 3-product 256^2, v3 (round-10 exact)
    gemm3s_kernel<0><<<dim3(H1 / 256, B / 256, 1), 512, 0, stream>>>(
        xh, xl, W0Th, W0Tl, eb0, nullptr, h1h, h1l, B, H1, D, D);
    // G2: stage-once 3-product, split-K x2 -> fp32 partials
    gemm3s_kernel<4><<<dim3(H2 / 256, B / 256, 2), 512, 0, stream>>>(
        h1h, h1l, W1Th, W1Tl, nullptr, p0, nullptr, nullptr, B, H2, H1 / 2, H1);
    // top-k mask fused with partial-add + bias + sigmoid
    topk_kernel<1><<<B, 256, 0, stream>>>(p0, p0 + (size_t)B * H2, eb1, hm, H2, KSEL);
    // G3: plain bf16 gemm8p v2 (5-barrier, kept)
    gemm8p_kernel<1, 2><<<dim3(H1 / 256, B / 256), 512, 0, stream>>>(
        hm, nullptr, dW1T, nullptr, db1, nullptr, dd, nullptr, B, H1, H2);
    // G4: plain bf16 gemm8p v2, fp32 out
    gemm8p_kernel<1, 3><<<dim3(D / 256, B / 256), 512, 0, stream>>>(
        dd, nullptr, dW0T, nullptr, db0, out, nullptr, nullptr, B, D, H1);
    return;
  }

  // ---------------- fallback: round-1 pipeline ----------------
  size_t off = 0;
  char* base = (char*)d_ws;
  auto alloc = [&](size_t bytes) -> char* {
    char* p2 = base + off;
    off += (bytes + 255) & ~(size_t)255;
    return p2;
  };
  u16* W0Th = (u16*)alloc((size_t)H1 * D * 2);
  u16* W0Tl = (u16*)alloc((size_t)H1 * D * 2);
  u16* W1Th = (u16*)alloc((size_t)H2 * H1 * 2);
  u16* W1Tl = (u16*)alloc((size_t)H2 * H1 * 2);
  u16* dW1T = (u16*)alloc((size_t)H1 * H2 * 2);
  u16* dW0T = (u16*)alloc((size_t)D * H1 * 2);
  u16* h1h  = (u16*)alloc((size_t)B * H1 * 2);
  u16* h1l  = (u16*)alloc((size_t)B * H1 * 2);
  float* h2 = (float*)alloc((size_t)B * H2 * 4);
  u16* hm   = (u16*)alloc((size_t)B * H2 * 2);
  u16* dd   = (u16*)alloc((size_t)B * H1 * 2);
  size_t need_x = 2 * (((size_t)B * D * 2 + 255) & ~(size_t)255);
  bool presplit = (off + need_x) <= ws_size;
  u16 *xh = nullptr, *xl = nullptr;
  if (presplit) {
    xh = (u16*)alloc((size_t)B * D * 2);
    xl = (u16*)alloc((size_t)B * D * 2);
  }

  wsplitT_kernel<1><<<dim3(H1 / 32, D / 32), tb, 0, stream>>>(eW0, W0Th, W0Tl, D, H1);
  wsplitT_kernel<1><<<dim3(H2 / 32, H1 / 32), tb, 0, stream>>>(eW1, W1Th, W1Tl, H1, H2);
  wsplitT_kernel<0><<<dim3(H1 / 32, H2 / 32), tb, 0, stream>>>(dW1, dW1T, nullptr, H2, H1);
  wsplitT_kernel<0><<<dim3(D / 32, H1 / 32), tb, 0, stream>>>(dW0, dW0T, nullptr, H1, D);

  if (presplit) {
    size_t n = (size_t)B * D;
    split_kernel<<<(unsigned)(n / (256 * 8)), 256, 0, stream>>>(x, xh, xl, n);
    gemm_kernel<1, 1, 0><<<dim3(H1 / 128, B / 128), 256, 0, stream>>>(
        nullptr, xh, xl, W0Th, W0Tl, eb0, nullptr, h1h, h1l, B, H1, D);
  } else {
    gemm_kernel<0, 1, 0><<<dim3(H1 / 128, B / 128), 256, 0, stream>>>(
        x, nullptr, nullptr, W0Th, W0Tl, eb0, nullptr, h1h, h1l, B, H1, D);
  }
  gemm_kernel<1, 1, 1><<<dim3(H2 / 128, B / 128), 256, 0, stream>>>(
      nullptr, h1h, h1l, W1Th, W1Tl, eb1, h2, nullptr, nullptr, B, H2, H1);
  topk_kernel<0><<<B, 256, 0, stream>>>(h2, nullptr, nullptr, hm, H2, KSEL);
  gemm_kernel<2, 0, 2><<<dim3(H1 / 128, B / 128), 256, 0, stream>>>(
      nullptr, hm, nullptr, dW1T, nullptr, db1, nullptr, dd, nullptr, B, H1, H2);
  gemm_kernel<2, 0, 3><<<dim3(D / 128, B / 128), 256, 0, stream>>>(
      nullptr, dd, nullptr, dW0T, nullptr, db0, out, nullptr, nullptr, B, D, H1);
}